// Round 3
// baseline (92.975 us; speedup 1.0000x reference)
//
#include <hip/hip_runtime.h>

#define KS 5
#define BETA 15.0f
#define LOG2E 1.4426950408889634f
#define LN2 0.6931471805599453f
#define SHIFT 16.0f

// DIAGNOSTIC ROUND: identical kernel to round 2, launched 3x back-to-back.
// dur_us = harness_overhead + 3*K  (round 2 gave overhead + K = 73.0 us).
// Purpose: decompose dur_us into harness floor vs kernel cost K. The kernel
// is idempotent (out fully overwritten, x read-only) so 3x launch is safe.

__global__ __launch_bounds__(256) void morph_soft_dilate(
    const float* __restrict__ x,
    const float* __restrict__ wy,
    float* __restrict__ out)
{
    const int tid   = threadIdx.x;
    const int plane = blockIdx.x >> 2;         // b*64 + c
    const int rb    = blockIdx.x & 3;
    const int c     = plane & 63;
    const float scale = BETA * LOG2E;

    // Wave-uniform dilated weights -> SGPRs via BITCAST readfirstlane.
    float W[25];
#pragma unroll
    for (int t = 0; t < 25; ++t) {
        const float wv = __builtin_amdgcn_exp2f(wy[c * 25 + t] * scale);
        W[t] = __int_as_float(__builtin_amdgcn_readfirstlane(__float_as_int(wv)));
    }

    const int tx = tid & 31;          // colgroup: cols 4tx..4tx+3
    const int ty = tid >> 5;          // strip 0..7
    const int wc = tx * 4;
    const int h0 = rb * 32 + ty * 4;  // first output row
    const float* xp = x + (size_t)plane * 16384;
    float* op = out + (size_t)plane * 16384;
    const bool lok = (tx > 0);
    const bool rok = (tx < 31);

    auto loadRaw = [&](int row, float* xv) {
        const int rc = row < 0 ? 0 : (row > 127 ? 127 : row);
        const float* rp = xp + rc * 128 + wc;
        const float2 a = *(const float2*)(rp - (lok ? 2 : 0));
        const float4 b = *(const float4*)rp;
        const float2 d = *(const float2*)(rp + (rok ? 4 : 2));
        const bool rv = (unsigned)row < 128u;
        const bool lv = lok && rv;
        const bool rv2 = rok && rv;
        xv[0] = lv ? a.x : 0.0f;
        xv[1] = lv ? a.y : 0.0f;
        xv[2] = rv ? b.x : 0.0f;
        xv[3] = rv ? b.y : 0.0f;
        xv[4] = rv ? b.z : 0.0f;
        xv[5] = rv ? b.w : 0.0f;
        xv[6] = rv2 ? d.x : 0.0f;
        xv[7] = rv2 ? d.y : 0.0f;
    };

    auto cvtE = [&](const float* xv, float* E) {
#pragma unroll
        for (int k = 0; k < 8; ++k)
            E[k] = __builtin_amdgcn_exp2f(fmaf(xv[k], scale, -SHIFT));
    };

    float win[5][8];
    float nxt[8];

    {
        float r[4][8];
#pragma unroll
        for (int k = 0; k < 4; ++k) loadRaw(h0 - 2 + k, r[k]);
        loadRaw(h0 + 2, nxt);
#pragma unroll
        for (int k = 0; k < 4; ++k) cvtE(r[k], win[k]);
    }

    const float kk = LN2 / BETA;
#pragma unroll
    for (int s = 0; s < 4; ++s) {
        cvtE(nxt, win[(4 + s) % 5]);
        if (s < 3) loadRaw(h0 + 3 + s, nxt);

        float a0 = 0.0f, a1 = 0.0f, a2 = 0.0f, a3 = 0.0f;
#pragma unroll
        for (int i = 0; i < KS; ++i) {
            const float* e = win[(s + i) % 5];
#pragma unroll
            for (int j = 0; j < KS; ++j) {
                const float wv = W[i * KS + j];
                a0 = fmaf(wv, e[j + 0], a0);
                a1 = fmaf(wv, e[j + 1], a1);
                a2 = fmaf(wv, e[j + 2], a2);
                a3 = fmaf(wv, e[j + 3], a3);
            }
        }

        float4 o;
        o.x = (__builtin_amdgcn_logf(a0) + SHIFT) * kk;
        o.y = (__builtin_amdgcn_logf(a1) + SHIFT) * kk;
        o.z = (__builtin_amdgcn_logf(a2) + SHIFT) * kk;
        o.w = (__builtin_amdgcn_logf(a3) + SHIFT) * kk;
        *(float4*)(op + (h0 + s) * 128 + wc) = o;
    }
}

extern "C" void kernel_launch(void* const* d_in, const int* in_sizes, int n_in,
                              void* d_out, int out_size, void* d_ws, size_t ws_size,
                              hipStream_t stream) {
    const float* x  = (const float*)d_in[0];
    const float* wy = (const float*)d_in[1];
    float* out      = (float*)d_out;

    // 3x identical launch: dur_us = overhead + 3K. Compare vs round 2
    // (overhead + K = 73.0 us) to solve for K and the harness floor.
    morph_soft_dilate<<<256 * 4, 256, 0, stream>>>(x, wy, out);
    morph_soft_dilate<<<256 * 4, 256, 0, stream>>>(x, wy, out);
    morph_soft_dilate<<<256 * 4, 256, 0, stream>>>(x, wy, out);
}

// Round 5
// 72.782 us; speedup vs baseline: 1.2774x; 1.2774x over previous
//
#include <hip/hip_runtime.h>

#define KS 5
#define BETA 15.0f
#define LOG2E 1.4426950408889634f
#define LN2 0.6931471805599453f
#define SHIFT 16.0f

// y = logsumexp_{25 taps}((w + x_pad)*BETA)/BETA, zero padding.
// Exp-domain: E = 2^(x*scale - 16) (pad x=0 -> E=2^-16 exactly),
// W_t = 2^(w_t*scale) in SGPRs, y = (log2(sum W_t*E_t) + 16)*ln2/BETA.
// Round-4 changes (decomposition showed K~=10us, latency-bound at 28% issue):
//  1. ALL 8 row-loads issued in the prologue; counted vmcnt lets each cvtE
//     wait only for its own row -> one HBM stall per wave instead of four.
//  2. Weight prep lane-parallel: lane t computes exp2(w_t), 25 v_readlane
//     broadcasts to SGPRs (replaces 25 serial exp2 per thread).
// Thread = 4 cols x 4 rows strip; 5x8 E-window slides down in registers.
// Block 256 = 32 colgroups x 8 strips -> 32 rows; grid = 256 planes x 4.
// (Round 4 was an infra failure — this is an unchanged resubmit.)

__global__ __launch_bounds__(256) void morph_soft_dilate(
    const float* __restrict__ x,
    const float* __restrict__ wy,
    float* __restrict__ out)
{
    const int tid   = threadIdx.x;
    const int plane = blockIdx.x >> 2;         // b*64 + c
    const int rb    = blockIdx.x & 3;
    const int c     = plane & 63;
    const float scale = BETA * LOG2E;

    // Lane-parallel weight exp2: lane t (t<25) computes W_t, broadcast via
    // readlane (bitcast through int - readlane/readfirstlane are int(int)).
    const int lane = tid & 63;
    const int wl   = lane < 25 ? lane : 0;
    const float wv_mine =
        __builtin_amdgcn_exp2f(wy[c * 25 + wl] * scale);
    float W[25];
#pragma unroll
    for (int t = 0; t < 25; ++t)
        W[t] = __int_as_float(
            __builtin_amdgcn_readlane(__float_as_int(wv_mine), t));

    const int tx = tid & 31;          // colgroup: cols 4tx..4tx+3
    const int ty = tid >> 5;          // strip 0..7
    const int wc = tx * 4;
    const int h0 = rb * 32 + ty * 4;  // first output row
    const float* xp = x + (size_t)plane * 16384;
    float* op = out + (size_t)plane * 16384;
    const bool lok = (tx > 0);
    const bool rok = (tx < 31);

    // Branch-free raw-row load: clamp row for addressing, nudge halo pointers
    // in-range via cndmask, zero invalid lanes with selects after the load.
    auto loadRaw = [&](int row, float* xv) {
        const int rc = row < 0 ? 0 : (row > 127 ? 127 : row);
        const float* rp = xp + rc * 128 + wc;
        const float2 a = *(const float2*)(rp - (lok ? 2 : 0));
        const float4 b = *(const float4*)rp;
        const float2 d = *(const float2*)(rp + (rok ? 4 : 2));
        const bool rv = (unsigned)row < 128u;
        const bool lv = lok && rv;
        const bool rv2 = rok && rv;
        xv[0] = lv ? a.x : 0.0f;
        xv[1] = lv ? a.y : 0.0f;
        xv[2] = rv ? b.x : 0.0f;
        xv[3] = rv ? b.y : 0.0f;
        xv[4] = rv ? b.z : 0.0f;
        xv[5] = rv ? b.w : 0.0f;
        xv[6] = rv2 ? d.x : 0.0f;
        xv[7] = rv2 ? d.y : 0.0f;
    };

    auto cvtE = [&](const float* xv, float* E) {
#pragma unroll
        for (int k = 0; k < 8; ++k)
            E[k] = __builtin_amdgcn_exp2f(fmaf(xv[k], scale, -SHIFT));
    };

    float win[5][8];   // E-values for cols wc-2..wc+5, 5 input rows
    float nxt[4][8];   // raw x rows h0+2..h0+5, ALL in flight from prologue
                       // (indexed only by the unrolled s -> static, no scratch)

    // Prologue: issue loads for ALL 8 input rows, then convert the first 4.
    {
        float r[4][8];
#pragma unroll
        for (int k = 0; k < 4; ++k) loadRaw(h0 - 2 + k, r[k]);
#pragma unroll
        for (int k = 0; k < 4; ++k) loadRaw(h0 + 2 + k, nxt[k]);
#pragma unroll
        for (int k = 0; k < 4; ++k) cvtE(r[k], win[k]);
    }

    const float kk = LN2 / BETA;
#pragma unroll
    for (int s = 0; s < 4; ++s) {
        // Convert the pre-fetched row for this strip; later rows' loads
        // remain outstanding (compiler emits counted vmcnt, not vmcnt(0)).
        cvtE(nxt[s], win[(4 + s) % 5]);

        float a0 = 0.0f, a1 = 0.0f, a2 = 0.0f, a3 = 0.0f;
#pragma unroll
        for (int i = 0; i < KS; ++i) {
            const float* e = win[(s + i) % 5];
#pragma unroll
            for (int j = 0; j < KS; ++j) {
                const float wv = W[i * KS + j];
                a0 = fmaf(wv, e[j + 0], a0);
                a1 = fmaf(wv, e[j + 1], a1);
                a2 = fmaf(wv, e[j + 2], a2);
                a3 = fmaf(wv, e[j + 3], a3);
            }
        }

        float4 o;
        o.x = (__builtin_amdgcn_logf(a0) + SHIFT) * kk;
        o.y = (__builtin_amdgcn_logf(a1) + SHIFT) * kk;
        o.z = (__builtin_amdgcn_logf(a2) + SHIFT) * kk;
        o.w = (__builtin_amdgcn_logf(a3) + SHIFT) * kk;
        *(float4*)(op + (h0 + s) * 128 + wc) = o;
    }
}

extern "C" void kernel_launch(void* const* d_in, const int* in_sizes, int n_in,
                              void* d_out, int out_size, void* d_ws, size_t ws_size,
                              hipStream_t stream) {
    const float* x  = (const float*)d_in[0];
    const float* wy = (const float*)d_in[1];
    float* out      = (float*)d_out;

    // 256 planes x 4 row-blocks of 32 rows
    morph_soft_dilate<<<256 * 4, 256, 0, stream>>>(x, wy, out);
}